// Round 1
// baseline (579.495 us; speedup 1.0000x reference)
//
#include <hip/hip_runtime.h>

typedef float f32x4 __attribute__((ext_vector_type(4)));
typedef short s16x8 __attribute__((ext_vector_type(8)));
typedef short s16x4 __attribute__((ext_vector_type(4)));

// Problem constants
#define M_TOT 16384
#define K_IN  4096
#define R_DIM 128
#define N_OUT 4096

__device__ __forceinline__ short sign_bf16(float v) {
  return v > 0.f ? (short)0x3F80 : (v < 0.f ? (short)0xBF80 : (short)0);
}

// round-to-nearest-even f32 -> bf16 hi, plus bf16(lo) of the residual
__device__ __forceinline__ void f32_to_bf16_pair(float f, short& h, short& l) {
  unsigned u = __float_as_uint(f);
  unsigned r = u + 0x7fffu + ((u >> 16) & 1u);
  h = (short)(r >> 16);
  float fh = __uint_as_float(r & 0xffff0000u);
  float fl = f - fh;
  unsigned u2 = __float_as_uint(fl);
  unsigned r2 = u2 + 0x7fffu + ((u2 >> 16) & 1u);
  l = (short)(r2 >> 16);
}

// ---------------- prep: VsT[r][k] = sign(V[k][r]); Us[n][r] = sign(U[n][r]) ----
__global__ __launch_bounds__(256)
void k_prep(const float* __restrict__ U, const float* __restrict__ V,
            short* __restrict__ VsT, short* __restrict__ Us) {
  int i = blockIdx.x * 256 + threadIdx.x;   // 0 .. 524287
  if (i < R_DIM * K_IN) {
    int n = i >> 12;          // r index 0..127
    int k = i & 4095;         // k index
    VsT[i] = sign_bf16(V[(size_t)k * R_DIM + n]);
    Us[i]  = sign_bf16(U[i]);
  }
}

// ---------------- kernel 1: Z[m][r] = sum_k x[m][k]*s2[k]*sign(V[k][r]) -------
// BM=32, BK=64, 512 threads (8 waves). grid = 512 blocks -> 2 blocks/CU.
// waves: mg = w&1 (16-row group), nq = w>>1 (32-col quarter of R=128)
__global__ __launch_bounds__(512, 4)
void k1_z(const float* __restrict__ x, const float* __restrict__ s2,
          const short* __restrict__ VsT, float* __restrict__ Z) {
  __shared__ short Ahi[32 * 64];          // 4 KB, row = 128 B, XOR-swizzled
  __shared__ short Alo[32 * 64];          // 4 KB
  __shared__ short Bt[128 * 64];          // 16 KB, row = 128 B, XOR-swizzled

  const int t = threadIdx.x;
  const int lane = t & 63;
  const int wave = t >> 6;
  const int m0 = blockIdx.x * 32;

  // A staging map: thread -> (row sr, 4 f32 at sk)
  const int sr = t >> 4;                  // 0..31
  const int sk = (t & 15) * 4;            // f32 offset in 64-wide k tile
  const float* xrow = x + (size_t)(m0 + sr) * K_IN + sk;
  const int aoff = sr * 128 + (((t & 15) * 8) ^ ((sr & 7) << 4));

  // B staging map: thread -> (row bn of VsT, 32 bytes at bkb)
  const int bn = t >> 2;                  // 0..127
  const int bkb = (t & 3) * 32;           // byte offset in 128 B row
  const char* vrow = (const char*)VsT + (size_t)bn * (K_IN * 2) + bkb;
  const int bsw = (bn & 7) << 4;
  const int boff0 = bn * 128 + (bkb ^ bsw);
  const int boff1 = bn * 128 + ((bkb + 16) ^ bsw);

  // fragment map
  const int mg = wave & 1;
  const int nq = wave >> 1;
  const int fr = mg * 16 + (lane & 15);   // A row 0..31
  const int rsw = (lane & 7) << 4;        // swizzle for all frag reads
  const int kgrp = (lane >> 4) * 16;      // byte offset of this lane's 8-k group
  const int bn0 = nq * 32 + (lane & 15);
  const int bn1 = bn0 + 16;

  f32x4 acc0 = {0.f, 0.f, 0.f, 0.f};
  f32x4 acc1 = {0.f, 0.f, 0.f, 0.f};

  // prologue: prefetch tile kt=0
  f32x4 xa = *(const f32x4*)xrow;
  f32x4 sa = *(const f32x4*)(s2 + sk);
  s16x8 v0 = *(const s16x8*)(vrow);
  s16x8 v1 = *(const s16x8*)(vrow + 16);

  for (int kt = 0; kt < 64; ++kt) {
    __syncthreads();                       // prev readers done
    // stage A (convert in regs) + B
    {
      s16x4 h4, l4;
#pragma unroll
      for (int j = 0; j < 4; ++j) {
        float f = xa[j] * sa[j];
        short hh, ll;
        f32_to_bf16_pair(f, hh, ll);
        h4[j] = hh; l4[j] = ll;
      }
      *(s16x4*)((char*)Ahi + aoff) = h4;
      *(s16x4*)((char*)Alo + aoff) = l4;
      *(s16x8*)((char*)Bt + boff0) = v0;
      *(s16x8*)((char*)Bt + boff1) = v1;
    }
    __syncthreads();                       // tiles visible
    // prefetch next tile (in flight across compute)
    const int ktn = (kt + 1) & 63;         // wrap: harmless redundant load
    f32x4 xan = *(const f32x4*)(xrow + ktn * 64);
    f32x4 san = *(const f32x4*)(s2 + ktn * 64 + sk);
    s16x8 v0n = *(const s16x8*)(vrow + ktn * 128);
    s16x8 v1n = *(const s16x8*)(vrow + ktn * 128 + 16);
    // compute 64 k
#pragma unroll
    for (int ks = 0; ks < 2; ++ks) {
      const int kb = ks * 64 + kgrp;
      s16x8 ah = *(const s16x8*)((const char*)Ahi + fr * 128 + (kb ^ rsw));
      s16x8 al = *(const s16x8*)((const char*)Alo + fr * 128 + (kb ^ rsw));
      s16x8 b0 = *(const s16x8*)((const char*)Bt + bn0 * 128 + (kb ^ rsw));
      s16x8 b1 = *(const s16x8*)((const char*)Bt + bn1 * 128 + (kb ^ rsw));
      acc0 = __builtin_amdgcn_mfma_f32_16x16x32_bf16(ah, b0, acc0, 0, 0, 0);
      acc0 = __builtin_amdgcn_mfma_f32_16x16x32_bf16(al, b0, acc0, 0, 0, 0);
      acc1 = __builtin_amdgcn_mfma_f32_16x16x32_bf16(ah, b1, acc1, 0, 0, 0);
      acc1 = __builtin_amdgcn_mfma_f32_16x16x32_bf16(al, b1, acc1, 0, 0, 0);
    }
    xa = xan; sa = san; v0 = v0n; v1 = v1n;
  }

  // epilogue: C layout col = lane&15, row = (lane>>4)*4 + j
  const int col0 = nq * 32 + (lane & 15);
  const int rowb = m0 + mg * 16 + (lane >> 4) * 4;
#pragma unroll
  for (int j = 0; j < 4; ++j) {
    Z[(size_t)(rowb + j) * R_DIM + col0]      = acc0[j];
    Z[(size_t)(rowb + j) * R_DIM + col0 + 16] = acc1[j];
  }
}

// ---------------- kernel 2: out[m][n] = (sum_r Z[m][r]*sign(U[n][r]))*s1[n]+bias[n]
// BM=128, BN=256, K=128 (whole K in LDS once). 512 threads (8 waves), grid 2048.
__global__ __launch_bounds__(512, 4)
void k2_out(const float* __restrict__ Z, const short* __restrict__ Us,
            const float* __restrict__ s1, const float* __restrict__ bias,
            float* __restrict__ out) {
  __shared__ short Zhi[128 * 128];         // 32 KB, row = 256 B, XOR-swizzled
  __shared__ short Zlo[128 * 128];         // 32 KB

  const int t = threadIdx.x;
  const int lane = t & 63;
  const int wave = t >> 6;
  const int bid = blockIdx.x;
  const int nb = bid & 15;                 // n-fast: consecutive blocks share Z tile
  const int mb = bid >> 4;
  const int m0 = mb * 128, n0 = nb * 256;
  const int wm = wave & 1, wn = wave >> 1; // 64-row half x 64-col quarter

  // B fragments held in registers: 4 ks x 4 nf
  s16x8 bf[4][4];
#pragma unroll
  for (int ks = 0; ks < 4; ++ks) {
#pragma unroll
    for (int nf = 0; nf < 4; ++nf) {
      const int n = n0 + wn * 64 + nf * 16 + (lane & 15);
      bf[ks][nf] = *(const s16x8*)(Us + (size_t)n * R_DIM + ks * 32 + (lane >> 4) * 8);
    }
  }

  // stage Z tile -> hi/lo bf16 LDS (swizzled)
  {
    const int sr = t >> 2;                 // 0..127
    const int skf = (t & 3) * 32;          // f32 offset
    const float* zrow = Z + (size_t)(m0 + sr) * R_DIM + skf;
    const int swr = (sr & 7) << 4;
#pragma unroll
    for (int q = 0; q < 4; ++q) {
      f32x4 a = *(const f32x4*)(zrow + q * 8);
      f32x4 b = *(const f32x4*)(zrow + q * 8 + 4);
      s16x8 h, l;
#pragma unroll
      for (int j = 0; j < 4; ++j) {
        short hh, ll;
        f32_to_bf16_pair(a[j], hh, ll); h[j] = hh;     l[j] = ll;
        f32_to_bf16_pair(b[j], hh, ll); h[j + 4] = hh; l[j + 4] = ll;
      }
      const int off = sr * 256 + ((((t & 3) * 64) + q * 16) ^ swr);
      *(s16x8*)((char*)Zhi + off) = h;
      *(s16x8*)((char*)Zlo + off) = l;
    }
  }
  __syncthreads();

  f32x4 acc[4][4] = {};
  const int rsw = (lane & 7) << 4;
  const int kg = (lane >> 4) * 16;
#pragma unroll
  for (int mf = 0; mf < 4; ++mf) {
    const int r = wm * 64 + mf * 16 + (lane & 15);
    const int rbase = r * 256;
#pragma unroll
    for (int ks = 0; ks < 4; ++ks) {
      const int kb = ks * 64 + kg;
      s16x8 ah = *(const s16x8*)((const char*)Zhi + rbase + (kb ^ rsw));
      s16x8 al = *(const s16x8*)((const char*)Zlo + rbase + (kb ^ rsw));
#pragma unroll
      for (int nf = 0; nf < 4; ++nf) {
        acc[mf][nf] = __builtin_amdgcn_mfma_f32_16x16x32_bf16(ah, bf[ks][nf], acc[mf][nf], 0, 0, 0);
        acc[mf][nf] = __builtin_amdgcn_mfma_f32_16x16x32_bf16(al, bf[ks][nf], acc[mf][nf], 0, 0, 0);
      }
    }
  }

  // epilogue: scale + bias, f32 stores
#pragma unroll
  for (int nf = 0; nf < 4; ++nf) {
    const int col = n0 + wn * 64 + nf * 16 + (lane & 15);
    const float sv = s1[col];
    const float bv = bias[col];
#pragma unroll
    for (int mf = 0; mf < 4; ++mf) {
      const int row = m0 + wm * 64 + mf * 16 + (lane >> 4) * 4;
#pragma unroll
      for (int j = 0; j < 4; ++j) {
        out[(size_t)(row + j) * N_OUT + col] = acc[mf][nf][j] * sv + bv;
      }
    }
  }
}

extern "C" void kernel_launch(void* const* d_in, const int* in_sizes, int n_in,
                              void* d_out, int out_size, void* d_ws, size_t ws_size,
                              hipStream_t stream) {
  const float* x    = (const float*)d_in[0];
  const float* U    = (const float*)d_in[1];
  const float* V    = (const float*)d_in[2];
  const float* s1   = (const float*)d_in[3];
  const float* s2   = (const float*)d_in[4];
  const float* bias = (const float*)d_in[5];
  float* out = (float*)d_out;

  // workspace layout: VsT (1 MB bf16) | Us (1 MB bf16) | Z (8 MB f32)
  short* VsT = (short*)d_ws;
  short* Us  = VsT + R_DIM * K_IN;
  float* Z   = (float*)(Us + N_OUT * R_DIM);

  k_prep<<<dim3(2048), dim3(256), 0, stream>>>(U, V, VsT, Us);
  k1_z<<<dim3(512), dim3(512), 0, stream>>>(x, s2, VsT, Z);
  k2_out<<<dim3(2048), dim3(512), 0, stream>>>(Z, Us, s1, bias, out);
}